// Round 1
// baseline (177.730 us; speedup 1.0000x reference)
//
#include <hip/hip_runtime.h>

// Per-class k-th order statistic via 4x8-bit radix select.
// th[c] = k_c-th smallest score among {score[i] : label[i]==c},
//         k_c = (int)((float)count_c * (float)(1.0 - eps_num/100.0))
// empty class -> global max score.

#define MAXC 256  // problem has class_num=100; support up to 256

__device__ unsigned int g_hist[MAXC * 256];
__device__ unsigned int g_prefix[MAXC];
__device__ int          g_remaining[MAXC];
__device__ unsigned int g_counts[MAXC];
__device__ unsigned int g_gmax;

__device__ __forceinline__ unsigned int fkey(float f) {
    unsigned int u = __float_as_uint(f);
    return (u & 0x80000000u) ? ~u : (u | 0x80000000u);
}
__device__ __forceinline__ float ikey(unsigned int u) {
    unsigned int b = (u & 0x80000000u) ? (u ^ 0x80000000u) : ~u;
    return __uint_as_float(b);
}

__global__ void init_kernel(const int* __restrict__ class_num_p) {
    int cn = *class_num_p;
    if (cn > MAXC) cn = MAXC;
    int total = cn * 256;
    for (int i = blockIdx.x * blockDim.x + threadIdx.x; i < total;
         i += gridDim.x * blockDim.x) {
        g_hist[i] = 0u;
    }
    if (blockIdx.x == 0 && threadIdx.x == 0) g_gmax = 0u;
}

template <int PASS>
__global__ void hist_kernel(const float* __restrict__ score,
                            const int* __restrict__ label, int n) {
    constexpr int SHIFT = 24 - 8 * PASS;
    int tid = blockIdx.x * blockDim.x + threadIdx.x;
    int stride = gridDim.x * blockDim.x;
    unsigned int lmax = 0u;

    int nvec = n >> 2;
    const float4* s4 = (const float4*)score;
    const int4*   l4 = (const int4*)label;
    for (int i = tid; i < nvec; i += stride) {
        float4 s = s4[i];
        int4   l = l4[i];
        float sv[4] = {s.x, s.y, s.z, s.w};
        int   lv[4] = {l.x, l.y, l.z, l.w};
#pragma unroll
        for (int j = 0; j < 4; ++j) {
            unsigned int u = fkey(sv[j]);
            int c = lv[j];
            if constexpr (PASS == 0) {
                lmax = lmax > u ? lmax : u;
                atomicAdd(&g_hist[(c << 8) | (u >> 24)], 1u);
            } else {
                if ((u >> (SHIFT + 8)) == (g_prefix[c] >> (SHIFT + 8)))
                    atomicAdd(&g_hist[(c << 8) | ((u >> SHIFT) & 0xFFu)], 1u);
            }
        }
    }
    // tail (n may not be divisible by 4)
    for (int i = (nvec << 2) + tid; i < n; i += stride) {
        unsigned int u = fkey(score[i]);
        int c = label[i];
        if constexpr (PASS == 0) {
            lmax = lmax > u ? lmax : u;
            atomicAdd(&g_hist[(c << 8) | (u >> 24)], 1u);
        } else {
            if ((u >> (SHIFT + 8)) == (g_prefix[c] >> (SHIFT + 8)))
                atomicAdd(&g_hist[(c << 8) | ((u >> SHIFT) & 0xFFu)], 1u);
        }
    }

    if constexpr (PASS == 0) {
        // wave-64 max reduction, then one atomic per wave
#pragma unroll
        for (int off = 32; off > 0; off >>= 1) {
            unsigned int o = (unsigned int)__shfl_xor((int)lmax, off, 64);
            lmax = lmax > o ? lmax : o;
        }
        if ((threadIdx.x & 63) == 0) atomicMax(&g_gmax, lmax);
    }
}

template <int PASS>
__global__ void select_kernel(const int* __restrict__ class_num_p,
                              const int* __restrict__ eps_p,
                              float* __restrict__ out) {
    int c = threadIdx.x;
    int cn = *class_num_p;
    if (cn > MAXC) cn = MAXC;
    if (c >= cn) return;
    constexpr int SHIFT = 24 - 8 * PASS;
    unsigned int* hist = &g_hist[c << 8];

    if constexpr (PASS == 0) {
        unsigned int count = 0u;
#pragma unroll 8
        for (int d = 0; d < 256; ++d) count += hist[d];
        g_counts[c] = count;
        // replicate JAX/NumPy weak-typed f32 arithmetic exactly:
        // f32(count) * f32(1.0 - eps_num/100.0), truncate toward zero
        double eps = (double)(*eps_p) / 100.0;
        float fac = (float)(1.0 - eps);
        float prod = (float)count * fac;
        g_remaining[c] = (int)prod;
        g_prefix[c] = 0u;
    }

    int rem = g_remaining[c];
    unsigned int cum = 0u;
    int chosen = 255;
    for (int d = 0; d < 256; ++d) {
        unsigned int h = hist[d];
        if (cum + h > (unsigned int)rem) { chosen = d; break; }
        cum += h;
    }
    // zero this class's histogram row for the next pass
#pragma unroll 8
    for (int d = 0; d < 256; ++d) hist[d] = 0u;

    g_remaining[c] = rem - (int)cum;
    unsigned int pref = g_prefix[c] | ((unsigned int)chosen << SHIFT);
    g_prefix[c] = pref;

    if constexpr (PASS == 3) {
        float v = (g_counts[c] == 0u) ? ikey(g_gmax) : ikey(pref);
        out[c] = v;
    }
}

extern "C" void kernel_launch(void* const* d_in, const int* in_sizes, int n_in,
                              void* d_out, int out_size, void* d_ws, size_t ws_size,
                              hipStream_t stream) {
    const float* score       = (const float*)d_in[0];
    const int*   label       = (const int*)d_in[1];
    const int*   class_num_p = (const int*)d_in[2];
    const int*   eps_p       = (const int*)d_in[3];
    float*       out         = (float*)d_out;
    int n = in_sizes[0];

    init_kernel<<<64, 256, 0, stream>>>(class_num_p);
    hist_kernel<0><<<512, 256, 0, stream>>>(score, label, n);
    select_kernel<0><<<1, 256, 0, stream>>>(class_num_p, eps_p, out);
    hist_kernel<1><<<512, 256, 0, stream>>>(score, label, n);
    select_kernel<1><<<1, 256, 0, stream>>>(class_num_p, eps_p, out);
    hist_kernel<2><<<512, 256, 0, stream>>>(score, label, n);
    select_kernel<2><<<1, 256, 0, stream>>>(class_num_p, eps_p, out);
    hist_kernel<3><<<512, 256, 0, stream>>>(score, label, n);
    select_kernel<3><<<1, 256, 0, stream>>>(class_num_p, eps_p, out);
}

// Round 2
// 44.928 us; speedup vs baseline: 3.9559x; 3.9559x over previous
//
#include <hip/hip_runtime.h>

// Per-class k-th order statistic (quantile) for Logit_Linear.get_th.
// Strategy: 8-bit coarse radix bucket (LDS-privatized histograms, NO global
// atomics in the streaming path) -> gather candidates of the selected bucket
// into compact per-class lists -> per-class 3x8-bit radix select in LDS.

#define MAXC      128        // supports class_num <= 128 (problem: 100)
#define G0        128        // scan0 blocks
#define T0        1024       // scan0 threads
#define GG        256        // gather blocks
#define TG        256        // gather threads
#define STAGE_CAP 12288      // candidates staged in LDS in final (48 KB)
#define CAND_CAP  (1u << 21) // candidate buffer words (covers n <= 2M)

__device__ unsigned int g_partial[G0 * MAXC * 128]; // packed u16 digit pairs
__device__ unsigned int g_blockmax[G0];
__device__ unsigned int g_bucket[MAXC];
__device__ int          g_rem[MAXC];
__device__ unsigned int g_bcount[MAXC];
__device__ unsigned int g_usemax[MAXC];
__device__ unsigned int g_ccursor[MAXC];
__device__ unsigned int g_cand[CAND_CAP];

__device__ __forceinline__ unsigned int fkey(float f) {
    unsigned int u = __float_as_uint(f);
    return (u & 0x80000000u) ? ~u : (u | 0x80000000u);
}
__device__ __forceinline__ float ikey(unsigned int u) {
    unsigned int b = (u & 0x80000000u) ? (u ^ 0x80000000u) : ~u;
    return __uint_as_float(b);
}

// ---------------------------------------------------------------- scan0 ----
// Per-class 8-bit histogram of fkey(score), privatized per block in LDS.
// Two u16 counters packed per u32 word: word (c*128 + d/2), half d&1.
// Per-block element count (<= ~7.9k) cannot overflow u16.
__global__ __launch_bounds__(T0) void scan0_kernel(const float* __restrict__ score,
                                                   const int* __restrict__ label,
                                                   int n, const int* __restrict__ cnp) {
    __shared__ unsigned int lhist[MAXC * 128];
    __shared__ unsigned int wmax[T0 / 64];
    int cn = *cnp; if (cn > MAXC) cn = MAXC;
    for (int i = threadIdx.x; i < MAXC * 128; i += T0) lhist[i] = 0u;
    __syncthreads();

    int per = ((n + G0 - 1) / G0 + 3) & ~3;
    int i0 = blockIdx.x * per;
    int i1 = min(n, i0 + per);
    unsigned int lmax = 0u;

    int nv = (i1 > i0) ? ((i1 - i0) >> 2) : 0;
    const float4* s4 = (const float4*)(score + i0);
    const int4*   l4 = (const int4*)(label + i0);
    for (int j = threadIdx.x; j < nv; j += T0) {
        float4 s = s4[j]; int4 l = l4[j];
        float sv[4] = {s.x, s.y, s.z, s.w};
        int   lv[4] = {l.x, l.y, l.z, l.w};
#pragma unroll
        for (int q = 0; q < 4; ++q) {
            unsigned int u = fkey(sv[q]);
            int c = lv[q] & (MAXC - 1);
            lmax = lmax > u ? lmax : u;
            atomicAdd(&lhist[(c << 7) | (u >> 25)], ((u >> 24) & 1u) ? 65536u : 1u);
        }
    }
    for (int i = i0 + (nv << 2) + threadIdx.x; i < i1; i += T0) {
        unsigned int u = fkey(score[i]);
        int c = label[i] & (MAXC - 1);
        lmax = lmax > u ? lmax : u;
        atomicAdd(&lhist[(c << 7) | (u >> 25)], ((u >> 24) & 1u) ? 65536u : 1u);
    }

    // block max (wave shfl reduce, then cross-wave via LDS)
#pragma unroll
    for (int off = 32; off; off >>= 1) {
        unsigned int o = (unsigned int)__shfl_xor((int)lmax, off, 64);
        lmax = lmax > o ? lmax : o;
    }
    if ((threadIdx.x & 63) == 0) wmax[threadIdx.x >> 6] = lmax;
    __syncthreads();
    if (threadIdx.x == 0) {
        unsigned int m = wmax[0];
        for (int w = 1; w < T0 / 64; ++w) m = m > wmax[w] ? m : wmax[w];
        g_blockmax[blockIdx.x] = m;
    }
    // non-atomic flush of this block's partial histogram
    unsigned int* dst = &g_partial[blockIdx.x * (MAXC * 128)];
    for (int i = threadIdx.x; i < (cn << 7); i += T0) dst[i] = lhist[i];
}

// -------------------------------------------------------------- select0 ----
// One block per class: reduce partials -> 256-bin hist -> count, k, bucket.
__global__ __launch_bounds__(256) void select0_kernel(const int* __restrict__ cnp,
                                                      const int* __restrict__ epsp) {
    int cn = *cnp; if (cn > MAXC) cn = MAXC;
    int c = blockIdx.x;
    if (c >= cn) return;
    int t = threadIdx.x;
    __shared__ unsigned int hist[256];
    __shared__ unsigned int scn[256];

    if (t < 128) {
        unsigned int lo = 0u, hi = 0u;
        const unsigned int* p = &g_partial[(c << 7) + t];
        for (int b = 0; b < G0; ++b) {
            unsigned int w = p[b * (MAXC * 128)];
            lo += w & 0xFFFFu; hi += w >> 16;
        }
        hist[2 * t] = lo; hist[2 * t + 1] = hi;
    }
    __syncthreads();
    scn[t] = hist[t]; __syncthreads();
    for (int off = 1; off < 256; off <<= 1) {
        unsigned int add = (t >= off) ? scn[t - off] : 0u;
        __syncthreads();
        scn[t] += add;
        __syncthreads();
    }
    unsigned int count = scn[255];
    // replicate JAX/NumPy weak-typed f32 arithmetic (exact in round 1)
    double eps = (double)(*epsp) / 100.0;
    float fac = (float)(1.0 - eps);
    int k = (int)((float)count * fac);
    int usemax = (count == 0u) || (k >= (int)count);
    if (t == 0) {
        g_usemax[c] = (unsigned)usemax;
        g_ccursor[c] = 0u;
        if (usemax) g_bcount[c] = 0u;
    }
    if (!usemax) {
        unsigned int incl = scn[t], excl = incl - hist[t];
        if ((unsigned)k >= excl && (unsigned)k < incl) {
            g_bucket[c] = (unsigned)t;
            g_rem[c]    = k - (int)excl;
            g_bcount[c] = hist[t];
        }
    }
}

// --------------------------------------------------------------- gather ----
// Two passes over this block's contiguous slice (2nd pass hits L1/L2):
// A) count matches per class in LDS; claim per-class global ranges with ONE
//    atomic per (block,class); B) write candidate keys compactly per class.
__global__ __launch_bounds__(TG) void gather_kernel(const float* __restrict__ score,
                                                    const int* __restrict__ label,
                                                    int n, const int* __restrict__ cnp) {
    int cn = *cnp; if (cn > MAXC) cn = MAXC;
    int t = threadIdx.x;
    __shared__ unsigned int sbucket[MAXC];
    __shared__ unsigned int scnt[MAXC];
    __shared__ unsigned int sbase[MAXC];
    __shared__ unsigned int scbase[MAXC];
    for (int c = t; c < cn; c += TG) {
        unsigned int um = g_usemax[c];
        sbucket[c] = um ? 0xFFFFFFFFu : g_bucket[c];
        scnt[c] = 0u;
        scbase[c] = um ? 0u : g_bcount[c];   // temp: per-class totals
    }
    __syncthreads();
    if (t == 0) {  // exclusive prefix over class totals -> global class bases
        unsigned int cb = 0u;
        for (int c = 0; c < cn; ++c) { unsigned int v = scbase[c]; scbase[c] = cb; cb += v; }
    }
    __syncthreads();

    int per = ((n + GG - 1) / GG + 3) & ~3;
    int i0 = blockIdx.x * per;
    int i1 = min(n, i0 + per);
    int nv = (i1 > i0) ? ((i1 - i0) >> 2) : 0;
    const float4* s4 = (const float4*)(score + i0);
    const int4*   l4 = (const int4*)(label + i0);

    // pass A: count
    for (int j = t; j < nv; j += TG) {
        float4 s = s4[j]; int4 l = l4[j];
        float sv[4] = {s.x, s.y, s.z, s.w};
        int   lv[4] = {l.x, l.y, l.z, l.w};
#pragma unroll
        for (int q = 0; q < 4; ++q) {
            unsigned int u = fkey(sv[q]);
            int c = lv[q] & (MAXC - 1);
            if ((u >> 24) == sbucket[c]) atomicAdd(&scnt[c], 1u);
        }
    }
    for (int i = i0 + (nv << 2) + t; i < i1; i += TG) {
        unsigned int u = fkey(score[i]);
        int c = label[i] & (MAXC - 1);
        if ((u >> 24) == sbucket[c]) atomicAdd(&scnt[c], 1u);
    }
    __syncthreads();
    for (int c = t; c < cn; c += TG) {
        unsigned int cnt = scnt[c];
        sbase[c] = cnt ? atomicAdd(&g_ccursor[c], cnt) : 0u;
        scnt[c] = 0u;   // reuse as local cursor
    }
    __syncthreads();
    // pass B: write
    for (int j = t; j < nv; j += TG) {
        float4 s = s4[j]; int4 l = l4[j];
        float sv[4] = {s.x, s.y, s.z, s.w};
        int   lv[4] = {l.x, l.y, l.z, l.w};
#pragma unroll
        for (int q = 0; q < 4; ++q) {
            unsigned int u = fkey(sv[q]);
            int c = lv[q] & (MAXC - 1);
            if ((u >> 24) == sbucket[c]) {
                unsigned int pos = atomicAdd(&scnt[c], 1u);
                g_cand[scbase[c] + sbase[c] + pos] = u;
            }
        }
    }
    for (int i = i0 + (nv << 2) + t; i < i1; i += TG) {
        unsigned int u = fkey(score[i]);
        int c = label[i] & (MAXC - 1);
        if ((u >> 24) == sbucket[c]) {
            unsigned int pos = atomicAdd(&scnt[c], 1u);
            g_cand[scbase[c] + sbase[c] + pos] = u;
        }
    }
}

// ---------------------------------------------------------------- final ----
// One block per class: 3x8-bit radix select over candidates (staged in LDS).
__global__ __launch_bounds__(256) void final_kernel(const int* __restrict__ cnp,
                                                    float* __restrict__ out) {
    int cn = *cnp; if (cn > MAXC) cn = MAXC;
    int c = blockIdx.x;
    if (c >= cn) return;
    int t = threadIdx.x;
    __shared__ unsigned int sh[256];
    __shared__ unsigned int ss[256];
    __shared__ unsigned int sel[2];
    __shared__ unsigned int scb[MAXC];
    __shared__ unsigned int scand[STAGE_CAP];

    if (g_usemax[c]) {  // empty class (or k>=count): global max score
        unsigned int v = (t < G0) ? g_blockmax[t] : 0u;
        sh[t] = v; __syncthreads();
        for (int off = 128; off; off >>= 1) {
            if (t < off) { unsigned a = sh[t + off]; if (a > sh[t]) sh[t] = a; }
            __syncthreads();
        }
        if (t == 0) out[c] = ikey(sh[0]);
        return;
    }

    for (int cc = t; cc < cn; cc += 256) scb[cc] = g_usemax[cc] ? 0u : g_bcount[cc];
    __syncthreads();
    if (t == 0) {
        unsigned int cb = 0u;
        for (int cc = 0; cc < cn; ++cc) { unsigned int v = scb[cc]; scb[cc] = cb; cb += v; }
    }
    __syncthreads();

    unsigned int base = scb[c], m = g_bcount[c], bucket = g_bucket[c];
    int rem = g_rem[c];
    const unsigned int* src;
    if (m <= STAGE_CAP) {
        for (unsigned int j = t; j < m; j += 256) scand[j] = g_cand[base + j];
        __syncthreads();
        src = scand;
    } else {
        src = &g_cand[base];
    }

    unsigned int pref = bucket << 24;
    for (int shift = 16; shift >= 0; shift -= 8) {
        sh[t] = 0u; __syncthreads();
        for (unsigned int j = t; j < m; j += 256) {
            unsigned int u = src[j];
            if ((u >> (shift + 8)) == (pref >> (shift + 8)))
                atomicAdd(&sh[(u >> shift) & 255u], 1u);
        }
        __syncthreads();
        ss[t] = sh[t]; __syncthreads();
        for (int off = 1; off < 256; off <<= 1) {
            unsigned int add = (t >= off) ? ss[t - off] : 0u;
            __syncthreads();
            ss[t] += add;
            __syncthreads();
        }
        unsigned int incl = ss[t], excl = incl - sh[t];
        if ((unsigned)rem >= excl && (unsigned)rem < incl) { sel[0] = (unsigned)t; sel[1] = excl; }
        __syncthreads();
        rem -= (int)sel[1];
        pref |= sel[0] << shift;
        __syncthreads();
    }
    if (t == 0) out[c] = ikey(pref);
}

extern "C" void kernel_launch(void* const* d_in, const int* in_sizes, int n_in,
                              void* d_out, int out_size, void* d_ws, size_t ws_size,
                              hipStream_t stream) {
    const float* score = (const float*)d_in[0];
    const int*   label = (const int*)d_in[1];
    const int*   cnp   = (const int*)d_in[2];
    const int*   epsp  = (const int*)d_in[3];
    float*       out   = (float*)d_out;
    int n = in_sizes[0];

    scan0_kernel <<<G0,   T0, 0, stream>>>(score, label, n, cnp);
    select0_kernel<<<MAXC, 256, 0, stream>>>(cnp, epsp);
    gather_kernel<<<GG,   TG, 0, stream>>>(score, label, n, cnp);
    final_kernel <<<MAXC, 256, 0, stream>>>(cnp, out);
}